// Round 1
// baseline (1576.895 us; speedup 1.0000x reference)
//
#include <hip/hip_runtime.h>
#include <hip/hip_bf16.h>
#include <math.h>

#define V 65536
#define G 2048
#define NPG 32
#define DEG 4
#define NE (V*DEG)
#define H 200
#define NODE_IN 74
#define EDGE_IN 12
#define NL 5

__device__ __forceinline__ float sigmoidf_(float x) { return 1.f / (1.f + __expf(-x)); }

// ---------------- node embedding: h = node_feat @ node_W + node_b ----------------
// 16 nodes per block; stage features in LDS; thread j owns output column j.
__global__ __launch_bounds__(256) void k_node_embed(const float* __restrict__ nf,
                                                    const float* __restrict__ W,
                                                    const float* __restrict__ b,
                                                    float* __restrict__ h) {
    __shared__ float fs[16][NODE_IN];
    const int tid = threadIdx.x;
    const int base = blockIdx.x * 16;
    for (int p = tid; p < 16 * NODE_IN; p += 256) {
        int n = p / NODE_IN, i = p - n * NODE_IN;
        fs[n][i] = nf[(base + n) * NODE_IN + i];
    }
    __syncthreads();
    const int j = tid;
    if (j < H) {
        float acc[16];
#pragma unroll
        for (int n = 0; n < 16; n++) acc[n] = 0.f;
        for (int i = 0; i < NODE_IN; i++) {
            float w = W[i * H + j];
#pragma unroll
            for (int n = 0; n < 16; n++) acc[n] = fmaf(fs[n][i], w, acc[n]);
        }
        float bj = b[j];
        for (int n = 0; n < 16; n++) h[(base + n) * H + j] = acc[n] + bj;
    }
}

// ---------------- one GNN layer (fused: edge-embed recompute + edge softmax + agg + matvec + relu + residual)
// One block per graph (32 nodes, 128 edges). Thread j owns feature column j.
__global__ __launch_bounds__(256) void k_gnn_layer(const float* __restrict__ hin,
                                                   float* __restrict__ hout,
                                                   const float* __restrict__ ef,
                                                   const int* __restrict__ src,
                                                   const float* __restrict__ eW,
                                                   const float* __restrict__ eb,
                                                   const float* __restrict__ W,
                                                   const float* __restrict__ b) {
    __shared__ float h_s[NPG][H];     // 25.6 KB
    __shared__ float agg_s[NPG][H];   // 25.6 KB
    __shared__ int src_s[NPG * DEG];  // 512 B   (total ~51.7 KB -> 3 blocks/CU)
    const int g = blockIdx.x, tid = threadIdx.x;
    const int nbase = g * NPG, ebase = g * NPG * DEG;

    for (int p = tid; p < NPG * H; p += 256) h_s[0][p] = hin[nbase * H + p];
    if (tid < NPG * DEG) src_s[tid] = src[ebase + tid] - nbase;  // src guaranteed in-graph
    __syncthreads();

    const int j = tid;
    if (j < H) {
        // per-thread copy of edge_W column j (12 values) + bias
        float ewr[EDGE_IN];
#pragma unroll
        for (int i = 0; i < EDGE_IN; i++) ewr[i] = eW[i * H + j];
        const float ebj = eb[j];

        for (int n = 0; n < NPG; n++) {
            float m[DEG];
#pragma unroll
            for (int k = 0; k < DEG; k++) {
                int e = n * DEG + k;
                float eh = ebj;
#pragma unroll
                for (int i = 0; i < EDGE_IN; i++)
                    eh = fmaf(ef[(ebase + e) * EDGE_IN + i], ewr[i], eh);  // uniform -> s_load
                m[k] = h_s[src_s[e]][j] + eh;
            }
            float mx = fmaxf(fmaxf(m[0], m[1]), fmaxf(m[2], m[3]));
            float den = 0.f, num = 0.f;
#pragma unroll
            for (int k = 0; k < DEG; k++) {
                float ex = __expf(m[k] - mx);
                den += ex;
                num = fmaf(m[k], ex, num);
            }
            agg_s[n][j] = num / den;
        }
    }
    __syncthreads();

    if (j < H) {
        float acc[NPG];
#pragma unroll
        for (int n = 0; n < NPG; n++) acc[n] = 0.f;
        for (int i = 0; i < H; i += 4) {
            float w0 = W[(i + 0) * H + j];
            float w1 = W[(i + 1) * H + j];
            float w2 = W[(i + 2) * H + j];
            float w3 = W[(i + 3) * H + j];
#pragma unroll
            for (int n = 0; n < NPG; n++) {
                float4 a4 = *reinterpret_cast<const float4*>(&agg_s[n][i]);  // broadcast b128
                acc[n] = fmaf(a4.x, w0, fmaf(a4.y, w1, fmaf(a4.z, w2, fmaf(a4.w, w3, acc[n]))));
            }
        }
        float bj = b[j];
        for (int n = 0; n < NPG; n++) {
            float v = acc[n] + bj;
            v = v > 0.f ? v : 0.f;
            hout[(nbase + n) * H + j] = v + h_s[n][j];
        }
    }
}

// ---------------- gf init: gf[g] = sum over graph's 32 nodes ----------------
__global__ __launch_bounds__(256) void k_gf_init(const float* __restrict__ h, float* __restrict__ gf) {
    const int g = blockIdx.x, j = threadIdx.x;
    if (j < H) {
        float s = 0.f;
        for (int n = 0; n < NPG; n++) s += h[(g * NPG + n) * H + j];
        gf[g * H + j] = s;
    }
}

// ---------------- readout attention (per t): z -> softmax_nodes -> wh -> ctx ----------------
// One block per graph. Uses sum(a)=1 identity: ctx = elu((sum_v a_v h_v) @ pr_W + pr_b).
__global__ __launch_bounds__(256) void k_attn(const float* __restrict__ h,
                                              const float* __restrict__ gf,
                                              const float* __restrict__ lgW,  // [2H]
                                              const float* __restrict__ lgb,  // [1]
                                              const float* __restrict__ prW,  // [H][H]
                                              const float* __restrict__ prb,  // [H]
                                              float* __restrict__ ctx_out) {
    __shared__ float h_s[NPG][H];
    __shared__ float gf_s[H];
    __shared__ float zp[256];
    __shared__ float z_s[NPG];
    __shared__ float a_s[NPG];
    __shared__ float wh_s[H];
    const int g = blockIdx.x, tid = threadIdx.x;

    for (int p = tid; p < NPG * H; p += 256) h_s[0][p] = h[g * NPG * H + p];
    if (tid < H) gf_s[tid] = gf[g * H + tid];
    __syncthreads();

    // c = dot(relu(gf), lgW[0:H]) -- redundantly computed by all threads (broadcast reads)
    float c = 0.f;
    for (int jj = 0; jj < H; jj++) c = fmaf(fmaxf(gf_s[jj], 0.f), lgW[jj], c);

    // z_n = leaky_relu(c + dot(h[n], lgW[H:2H]) + lgb), 8 threads per node
    {
        const int n = tid >> 3, l = tid & 7;
        float p = 0.f;
        for (int jj = l; jj < H; jj += 8) p = fmaf(h_s[n][jj], lgW[H + jj], p);
        zp[tid] = p;
    }
    __syncthreads();
    if (tid < NPG) {
        float z = c + lgb[0];
        for (int q = 0; q < 8; q++) z += zp[tid * 8 + q];
        z_s[tid] = z > 0.f ? z : 0.01f * z;
    }
    __syncthreads();
    float zmax = -1e30f;
    for (int n = 0; n < NPG; n++) zmax = fmaxf(zmax, z_s[n]);
    if (tid < NPG) a_s[tid] = __expf(z_s[tid] - zmax);
    __syncthreads();
    float den = 0.f;
    for (int n = 0; n < NPG; n++) den += a_s[n];

    if (tid < H) {
        float s = 0.f;
        for (int n = 0; n < NPG; n++) s = fmaf(a_s[n], h_s[n][tid], s);
        wh_s[tid] = s / den;
    }
    __syncthreads();

    if (tid < H) {
        float s = prb[tid];
        for (int i = 0; i < H; i++) s = fmaf(wh_s[i], prW[i * H + tid], s);
        ctx_out[g * H + tid] = s > 0.f ? s : __expf(s) - 1.f;  // elu
    }
}

// ---------------- GRU cell (per t): 8 graphs per block for weight reuse ----------------
#define GPB 8
#define GP 9  // padded stride for gate LDS
__global__ __launch_bounds__(256) void k_gru(const float* __restrict__ ctx,
                                             const float* __restrict__ gf,
                                             const float* __restrict__ Wih,  // [3H][H]
                                             const float* __restrict__ Whh,  // [3H][H]
                                             const float* __restrict__ bih,
                                             const float* __restrict__ bhh,
                                             float* __restrict__ gf_out) {
    __shared__ float ctx_s[GPB][H];
    __shared__ float gfs[GPB][H];
    __shared__ float gi_s[3 * H][GP];
    __shared__ float gh_s[3 * H][GP];
    const int gbase = blockIdx.x * GPB, tid = threadIdx.x;

    for (int p = tid; p < GPB * H; p += 256) {
        ctx_s[0][p] = ctx[gbase * H + p];
        gfs[0][p] = gf[gbase * H + p];
    }
    __syncthreads();

    for (int k = tid; k < 3 * H; k += 256) {
        float ai[GPB], ah[GPB];
        float bi = bih[k], bh = bhh[k];
#pragma unroll
        for (int q = 0; q < GPB; q++) { ai[q] = bi; ah[q] = bh; }
        for (int jj = 0; jj < H; jj++) {
            float wi = Wih[k * H + jj];
            float wh = Whh[k * H + jj];
#pragma unroll
            for (int q = 0; q < GPB; q++) {
                ai[q] = fmaf(ctx_s[q][jj], wi, ai[q]);
                ah[q] = fmaf(gfs[q][jj], wh, ah[q]);
            }
        }
#pragma unroll
        for (int q = 0; q < GPB; q++) { gi_s[k][q] = ai[q]; gh_s[k][q] = ah[q]; }
    }
    __syncthreads();

    for (int p = tid; p < GPB * H; p += 256) {
        int q = p / H, jj = p - q * H;  // jj fastest -> coalesced store
        float r = sigmoidf_(gi_s[jj][q] + gh_s[jj][q]);
        float u = sigmoidf_(gi_s[H + jj][q] + gh_s[H + jj][q]);
        float nn = tanhf(gi_s[2 * H + jj][q] + r * gh_s[2 * H + jj][q]);
        gf_out[(gbase + q) * H + jj] = (1.f - u) * nn + u * gfs[q][jj];
    }
}

extern "C" void kernel_launch(void* const* d_in, const int* in_sizes, int n_in,
                              void* d_out, int out_size, void* d_ws, size_t ws_size,
                              hipStream_t stream) {
    const float* node_feat = (const float*)d_in[0];
    const float* edge_feat = (const float*)d_in[1];
    const int* src = (const int*)d_in[2];
    // d_in[3] = dst (structure known: dst[e]=e/4), d_in[4] = graph_id (v/32)
    const float* node_W = (const float*)d_in[5];
    const float* node_b = (const float*)d_in[6];
    const float* edge_W = (const float*)d_in[7];
    const float* edge_b = (const float*)d_in[8];
    const float* gnn_W = (const float*)d_in[9];
    const float* gnn_b = (const float*)d_in[10];
    const float* lg_W = (const float*)d_in[11];
    const float* lg_b = (const float*)d_in[12];
    const float* pr_W = (const float*)d_in[13];
    const float* pr_b = (const float*)d_in[14];
    const float* W_ih = (const float*)d_in[15];
    const float* W_hh = (const float*)d_in[16];
    const float* b_ih = (const float*)d_in[17];
    const float* b_hh = (const float*)d_in[18];
    float* out = (float*)d_out;

    char* ws = (char*)d_ws;
    float* h_a = (float*)ws;
    float* h_b = (float*)(ws + (size_t)V * H * sizeof(float));
    float* gf_ws = (float*)(ws + (size_t)2 * V * H * sizeof(float));
    float* ctx_ws = gf_ws + (size_t)G * H;

    k_node_embed<<<V / 16, 256, 0, stream>>>(node_feat, node_W, node_b, h_a);

    const float* hin = h_a;
    float* hout = h_b;
    for (int l = 0; l < NL; l++) {
        k_gnn_layer<<<G, 256, 0, stream>>>(hin, hout, edge_feat, src, edge_W, edge_b,
                                           gnn_W + (size_t)l * H * H, gnn_b + (size_t)l * H);
        const float* t = hout;
        hout = (float*)hin;
        hin = t;
    }
    const float* hfin = hin;  // = h_b after 5 layers

    k_gf_init<<<G, 256, 0, stream>>>(hfin, gf_ws);
    for (int t = 0; t < 2; t++) {
        k_attn<<<G, 256, 0, stream>>>(hfin, gf_ws, lg_W + (size_t)t * 2 * H, lg_b + t,
                                      pr_W + (size_t)t * H * H, pr_b + (size_t)t * H, ctx_ws);
        float* gout = (t == 1) ? out : gf_ws;
        k_gru<<<G / GPB, 256, 0, stream>>>(ctx_ws, gf_ws, W_ih + (size_t)t * 3 * H * H,
                                           W_hh + (size_t)t * 3 * H * H, b_ih + (size_t)t * 3 * H,
                                           b_hh + (size_t)t * 3 * H, gout);
    }
}

// Round 2
// 1355.889 us; speedup vs baseline: 1.1630x; 1.1630x over previous
//
#include <hip/hip_runtime.h>
#include <hip/hip_bf16.h>
#include <math.h>

#define V 65536
#define G 2048
#define NPG 32
#define DEG 4
#define NE (V*DEG)
#define H 200
#define NODE_IN 74
#define EDGE_IN 12
#define NL 5

// padded GEMM dims for MFMA phase: M=32, N 200->208 (13 tiles), K 200->224 (7 ksteps)
#define KP 224
#define NP 208
#define AROW 232   // agg LDS row stride in ushort (116 words; 116%32=20 -> 2-way max, free)

typedef __attribute__((ext_vector_type(8))) short short8;
typedef __attribute__((ext_vector_type(4))) float floatx4;

__device__ __forceinline__ float sigmoidf_(float x) { return 1.f / (1.f + __expf(-x)); }

__device__ __forceinline__ unsigned f2bf_bits(float f) {
    unsigned u = __float_as_uint(f);
    return (u + 0x7fffu + ((u >> 16) & 1u)) >> 16;  // RNE
}
__device__ __forceinline__ float bf2f(unsigned bits) {
    return __uint_as_float(bits << 16);
}

// ---------------- node embedding: h = node_feat @ node_W + node_b ----------------
__global__ __launch_bounds__(256) void k_node_embed(const float* __restrict__ nf,
                                                    const float* __restrict__ W,
                                                    const float* __restrict__ b,
                                                    float* __restrict__ h) {
    __shared__ float fs[16][NODE_IN];
    const int tid = threadIdx.x;
    const int base = blockIdx.x * 16;
    for (int p = tid; p < 16 * NODE_IN; p += 256) {
        int n = p / NODE_IN, i = p - n * NODE_IN;
        fs[n][i] = nf[(base + n) * NODE_IN + i];
    }
    __syncthreads();
    const int j = tid;
    if (j < H) {
        float acc[16];
#pragma unroll
        for (int n = 0; n < 16; n++) acc[n] = 0.f;
        for (int i = 0; i < NODE_IN; i++) {
            float w = W[i * H + j];
#pragma unroll
            for (int n = 0; n < 16; n++) acc[n] = fmaf(fs[n][i], w, acc[n]);
        }
        float bj = b[j];
        for (int n = 0; n < 16; n++) h[(base + n) * H + j] = acc[n] + bj;
    }
}

// ---------------- W transpose + hi/lo bf16 split precompute ----------------
// Wt_hi/Wt_lo: [NL][NP][KP] bf16, Wt[l][n][k] = gnn_W[l][k][n] (zero padded)
__global__ __launch_bounds__(256) void k_prep_w(const float* __restrict__ gnnW,
                                                unsigned short* __restrict__ WtHi,
                                                unsigned short* __restrict__ WtLo) {
    int idx = blockIdx.x * 256 + threadIdx.x;
    if (idx >= NL * NP * KP) return;
    int l = idx / (NP * KP);
    int rem = idx - l * NP * KP;
    int n = rem / KP;
    int k = rem - n * KP;
    float w = (n < H && k < H) ? gnnW[l * H * H + k * H + n] : 0.f;
    unsigned hb = f2bf_bits(w);
    float hf = bf2f(hb);
    unsigned lb = f2bf_bits(w - hf);
    WtHi[idx] = (unsigned short)hb;
    WtLo[idx] = (unsigned short)lb;
}

// ---------------- one GNN layer: edge softmax agg (VALU) + agg@W via split-bf16 MFMA ----------------
__global__ __launch_bounds__(256, 2) void k_gnn_layer(const float* __restrict__ hin,
                                                      float* __restrict__ hout,
                                                      const float* __restrict__ ef,
                                                      const int* __restrict__ src,
                                                      const float* __restrict__ eW,
                                                      const float* __restrict__ eb,
                                                      const unsigned short* __restrict__ WtHi,
                                                      const unsigned short* __restrict__ WtLo,
                                                      const float* __restrict__ b) {
    __shared__ float h_s[NPG][H];                         // 25.6 KB (gather + residual)
    __shared__ alignas(16) unsigned short agg_hi[NPG * AROW];  // 14.8 KB
    __shared__ alignas(16) unsigned short agg_lo[NPG * AROW];  // 14.8 KB
    __shared__ int src_s[NPG * DEG];
    const int g = blockIdx.x, tid = threadIdx.x;
    const int nbase = g * NPG, ebase = g * NPG * DEG;

    for (int p = tid; p < NPG * H; p += 256) h_s[0][p] = hin[nbase * H + p];
    if (tid < NPG * DEG) src_s[tid] = src[ebase + tid] - nbase;
    // zero the K-pad region (k = 200..231 -> words 100..115 per row)
    for (int p = tid; p < NPG * 16; p += 256) {
        int row = p >> 4, w = p & 15;
        *(unsigned*)&agg_hi[row * AROW + (100 + w) * 2] = 0u;
        *(unsigned*)&agg_lo[row * AROW + (100 + w) * 2] = 0u;
    }
    __syncthreads();

    // ---- phase 1: edge embed recompute + per-node softmax-weighted agg, pack to bf16 hi/lo ----
    const int j = tid;
    if (j < H) {
        float ewr[EDGE_IN];
#pragma unroll
        for (int i = 0; i < EDGE_IN; i++) ewr[i] = eW[i * H + j];
        const float ebj = eb[j];

        for (int n = 0; n < NPG; n++) {
            float m[DEG];
#pragma unroll
            for (int k = 0; k < DEG; k++) {
                int e = n * DEG + k;
                float eh = ebj;
#pragma unroll
                for (int i = 0; i < EDGE_IN; i++)
                    eh = fmaf(ef[(ebase + e) * EDGE_IN + i], ewr[i], eh);  // uniform -> scalar loads
                m[k] = h_s[src_s[e]][j] + eh;
            }
            float mx = fmaxf(fmaxf(m[0], m[1]), fmaxf(m[2], m[3]));
            float den = 0.f, num = 0.f;
#pragma unroll
            for (int k = 0; k < DEG; k++) {
                float ex = __expf(m[k] - mx);
                den += ex;
                num = fmaf(m[k], ex, num);
            }
            float agg = num / den;
            // split into bf16 hi/lo; pack with partner lane (j^1); even lane writes hi word, odd writes lo word
            unsigned hb = f2bf_bits(agg);
            unsigned lb = f2bf_bits(agg - bf2f(hb));
            unsigned x = hb | (lb << 16);
            unsigned px = __shfl_xor((int)x, 1);
            unsigned word, off;
            if ((j & 1) == 0) {
                word = (x & 0xffffu) | (px << 16);           // hi_j | hi_{j+1}
                off = 0;
            } else {
                word = (px >> 16) | (x & 0xffff0000u);        // lo_{j-1} | lo_j
                off = 1;
            }
            unsigned short* base = off ? agg_lo : agg_hi;
            *(unsigned*)&base[n * AROW + (j >> 1) * 2] = word;
        }
    }
    __syncthreads();

    // ---- phase 2: C[32][200] = agg @ W via 16x16x32 bf16 MFMA, split-3 for ~fp32 accuracy ----
    const int wave = tid >> 6, lane = tid & 63;
    const int l15 = lane & 15, quad = lane >> 4;

    floatx4 acc[2][4];
#pragma unroll
    for (int mt = 0; mt < 2; mt++)
#pragma unroll
        for (int i = 0; i < 4; i++) acc[mt][i] = (floatx4){0.f, 0.f, 0.f, 0.f};

    const int ntcnt = (wave == 0) ? 4 : 3;  // n-tiles: wave, wave+4, wave+8 (, wave+12)

    for (int ks = 0; ks < KP / 32; ks++) {
        short8 a_hi[2], a_lo[2];
#pragma unroll
        for (int mt = 0; mt < 2; mt++) {
            int aoff = (mt * 16 + l15) * AROW + ks * 32 + quad * 8;
            a_hi[mt] = *reinterpret_cast<const short8*>(&agg_hi[aoff]);
            a_lo[mt] = *reinterpret_cast<const short8*>(&agg_lo[aoff]);
        }
#pragma unroll 4
        for (int i = 0; i < ntcnt; i++) {
            int nt = wave + 4 * i;
            int boff = (nt * 16 + l15) * KP + ks * 32 + quad * 8;
            short8 bh = *reinterpret_cast<const short8*>(&WtHi[boff]);
            short8 bl = *reinterpret_cast<const short8*>(&WtLo[boff]);
#pragma unroll
            for (int mt = 0; mt < 2; mt++) {
                acc[mt][i] = __builtin_amdgcn_mfma_f32_16x16x32_bf16(a_hi[mt], bh, acc[mt][i], 0, 0, 0);
                acc[mt][i] = __builtin_amdgcn_mfma_f32_16x16x32_bf16(a_lo[mt], bh, acc[mt][i], 0, 0, 0);
                acc[mt][i] = __builtin_amdgcn_mfma_f32_16x16x32_bf16(a_hi[mt], bl, acc[mt][i], 0, 0, 0);
            }
        }
    }

    // ---- epilogue: relu(C + b) + h residual -> hout.  C layout: col=lane&15, row=quad*4+r ----
    for (int i = 0; i < ntcnt; i++) {
        int nt = wave + 4 * i;
        int jj = nt * 16 + l15;
        if (jj < H) {
            float bj = b[jj];
#pragma unroll
            for (int mt = 0; mt < 2; mt++) {
#pragma unroll
                for (int r = 0; r < 4; r++) {
                    int node = mt * 16 + quad * 4 + r;
                    float v = acc[mt][i][r] + bj;
                    v = v > 0.f ? v : 0.f;
                    hout[(nbase + node) * H + jj] = v + h_s[node][jj];
                }
            }
        }
    }
}

// ---------------- gf init ----------------
__global__ __launch_bounds__(256) void k_gf_init(const float* __restrict__ h, float* __restrict__ gf) {
    const int g = blockIdx.x, j = threadIdx.x;
    if (j < H) {
        float s = 0.f;
        for (int n = 0; n < NPG; n++) s += h[(g * NPG + n) * H + j];
        gf[g * H + j] = s;
    }
}

// ---------------- readout attention ----------------
__global__ __launch_bounds__(256) void k_attn(const float* __restrict__ h,
                                              const float* __restrict__ gf,
                                              const float* __restrict__ lgW,
                                              const float* __restrict__ lgb,
                                              const float* __restrict__ prW,
                                              const float* __restrict__ prb,
                                              float* __restrict__ ctx_out) {
    __shared__ float h_s[NPG][H];
    __shared__ float gf_s[H];
    __shared__ float zp[256];
    __shared__ float z_s[NPG];
    __shared__ float a_s[NPG];
    __shared__ float wh_s[H];
    const int g = blockIdx.x, tid = threadIdx.x;

    for (int p = tid; p < NPG * H; p += 256) h_s[0][p] = h[g * NPG * H + p];
    if (tid < H) gf_s[tid] = gf[g * H + tid];
    __syncthreads();

    float c = 0.f;
    for (int jj = 0; jj < H; jj++) c = fmaf(fmaxf(gf_s[jj], 0.f), lgW[jj], c);

    {
        const int n = tid >> 3, l = tid & 7;
        float p = 0.f;
        for (int jj = l; jj < H; jj += 8) p = fmaf(h_s[n][jj], lgW[H + jj], p);
        zp[tid] = p;
    }
    __syncthreads();
    if (tid < NPG) {
        float z = c + lgb[0];
        for (int q = 0; q < 8; q++) z += zp[tid * 8 + q];
        z_s[tid] = z > 0.f ? z : 0.01f * z;
    }
    __syncthreads();
    float zmax = -1e30f;
    for (int n = 0; n < NPG; n++) zmax = fmaxf(zmax, z_s[n]);
    if (tid < NPG) a_s[tid] = __expf(z_s[tid] - zmax);
    __syncthreads();
    float den = 0.f;
    for (int n = 0; n < NPG; n++) den += a_s[n];

    if (tid < H) {
        float s = 0.f;
        for (int n = 0; n < NPG; n++) s = fmaf(a_s[n], h_s[n][tid], s);
        wh_s[tid] = s / den;
    }
    __syncthreads();

    if (tid < H) {
        float s = prb[tid];
        for (int i = 0; i < H; i++) s = fmaf(wh_s[i], prW[i * H + tid], s);
        ctx_out[g * H + tid] = s > 0.f ? s : __expf(s) - 1.f;
    }
}

// ---------------- GRU cell ----------------
#define GPB 8
#define GP 9
__global__ __launch_bounds__(256) void k_gru(const float* __restrict__ ctx,
                                             const float* __restrict__ gf,
                                             const float* __restrict__ Wih,
                                             const float* __restrict__ Whh,
                                             const float* __restrict__ bih,
                                             const float* __restrict__ bhh,
                                             float* __restrict__ gf_out) {
    __shared__ float ctx_s[GPB][H];
    __shared__ float gfs[GPB][H];
    __shared__ float gi_s[3 * H][GP];
    __shared__ float gh_s[3 * H][GP];
    const int gbase = blockIdx.x * GPB, tid = threadIdx.x;

    for (int p = tid; p < GPB * H; p += 256) {
        ctx_s[0][p] = ctx[gbase * H + p];
        gfs[0][p] = gf[gbase * H + p];
    }
    __syncthreads();

    for (int k = tid; k < 3 * H; k += 256) {
        float ai[GPB], ah[GPB];
        float bi = bih[k], bh = bhh[k];
#pragma unroll
        for (int q = 0; q < GPB; q++) { ai[q] = bi; ah[q] = bh; }
        for (int jj = 0; jj < H; jj++) {
            float wi = Wih[k * H + jj];
            float wh = Whh[k * H + jj];
#pragma unroll
            for (int q = 0; q < GPB; q++) {
                ai[q] = fmaf(ctx_s[q][jj], wi, ai[q]);
                ah[q] = fmaf(gfs[q][jj], wh, ah[q]);
            }
        }
#pragma unroll
        for (int q = 0; q < GPB; q++) { gi_s[k][q] = ai[q]; gh_s[k][q] = ah[q]; }
    }
    __syncthreads();

    for (int p = tid; p < GPB * H; p += 256) {
        int q = p / H, jj = p - q * H;
        float r = sigmoidf_(gi_s[jj][q] + gh_s[jj][q]);
        float u = sigmoidf_(gi_s[H + jj][q] + gh_s[H + jj][q]);
        float nn = tanhf(gi_s[2 * H + jj][q] + r * gh_s[2 * H + jj][q]);
        gf_out[(gbase + q) * H + jj] = (1.f - u) * nn + u * gfs[q][jj];
    }
}

extern "C" void kernel_launch(void* const* d_in, const int* in_sizes, int n_in,
                              void* d_out, int out_size, void* d_ws, size_t ws_size,
                              hipStream_t stream) {
    const float* node_feat = (const float*)d_in[0];
    const float* edge_feat = (const float*)d_in[1];
    const int* src = (const int*)d_in[2];
    const float* node_W = (const float*)d_in[5];
    const float* node_b = (const float*)d_in[6];
    const float* edge_W = (const float*)d_in[7];
    const float* edge_b = (const float*)d_in[8];
    const float* gnn_W = (const float*)d_in[9];
    const float* gnn_b = (const float*)d_in[10];
    const float* lg_W = (const float*)d_in[11];
    const float* lg_b = (const float*)d_in[12];
    const float* pr_W = (const float*)d_in[13];
    const float* pr_b = (const float*)d_in[14];
    const float* W_ih = (const float*)d_in[15];
    const float* W_hh = (const float*)d_in[16];
    const float* b_ih = (const float*)d_in[17];
    const float* b_hh = (const float*)d_in[18];
    float* out = (float*)d_out;

    char* ws = (char*)d_ws;
    float* h_a = (float*)ws;
    float* h_b = (float*)(ws + (size_t)V * H * sizeof(float));
    float* gf_ws = (float*)(ws + (size_t)2 * V * H * sizeof(float));
    float* ctx_ws = gf_ws + (size_t)G * H;
    unsigned short* WtHi = (unsigned short*)(ctx_ws + (size_t)G * H);
    unsigned short* WtLo = WtHi + (size_t)NL * NP * KP;

    {
        int total = NL * NP * KP;
        k_prep_w<<<(total + 255) / 256, 256, 0, stream>>>(gnn_W, WtHi, WtLo);
    }
    k_node_embed<<<V / 16, 256, 0, stream>>>(node_feat, node_W, node_b, h_a);

    const float* hin = h_a;
    float* hout = h_b;
    for (int l = 0; l < NL; l++) {
        k_gnn_layer<<<G, 256, 0, stream>>>(hin, hout, edge_feat, src, edge_W, edge_b,
                                           WtHi + (size_t)l * NP * KP, WtLo + (size_t)l * NP * KP,
                                           gnn_b + (size_t)l * H);
        const float* t = hout;
        hout = (float*)hin;
        hin = t;
    }
    const float* hfin = hin;

    k_gf_init<<<G, 256, 0, stream>>>(hfin, gf_ws);
    for (int t = 0; t < 2; t++) {
        k_attn<<<G, 256, 0, stream>>>(hfin, gf_ws, lg_W + (size_t)t * 2 * H, lg_b + t,
                                      pr_W + (size_t)t * H * H, pr_b + (size_t)t * H, ctx_ws);
        float* gout = (t == 1) ? out : gf_ws;
        k_gru<<<G / GPB, 256, 0, stream>>>(ctx_ws, gf_ws, W_ih + (size_t)t * 3 * H * H,
                                           W_hh + (size_t)t * 3 * H * H, b_ih + (size_t)t * 3 * H,
                                           b_hh + (size_t)t * 3 * H, gout);
    }
}